// Round 1
// baseline (1161.053 us; speedup 1.0000x reference)
//
#include <hip/hip_runtime.h>
#include <math.h>

#define Bn 8
#define Sn 2048
#define Hn 768
#define NSP 512
#define NROW 4096          // B * N_SPANS
#define SPAN_DIM 2688
#define S_IN_DIM 2706
#define NTYPE 18
#define NSENS 4

// ---------------- proposal head: [16384,768] @ [768,3] + b ----------------
__global__ __launch_bounds__(256) void proposal_kernel(
    const float* __restrict__ hidden, const float* __restrict__ Wp,
    const float* __restrict__ bp, float* __restrict__ out)
{
    int wave = threadIdx.x >> 6;
    int lane = threadIdx.x & 63;
    int row  = blockIdx.x * 4 + wave;       // < 16384
    const float* hrow = hidden + (size_t)row * Hn;
    float a0 = 0.f, a1 = 0.f, a2 = 0.f;
#pragma unroll
    for (int i = 0; i < Hn / 64; ++i) {
        int k = lane + i * 64;
        float h = hrow[k];
        a0 += h * Wp[k * 3 + 0];
        a1 += h * Wp[k * 3 + 1];
        a2 += h * Wp[k * 3 + 2];
    }
#pragma unroll
    for (int off = 32; off; off >>= 1) {
        a0 += __shfl_xor(a0, off);
        a1 += __shfl_xor(a1, off);
        a2 += __shfl_xor(a2, off);
    }
    if (lane < 3) {
        float v = (lane == 0 ? a0 : (lane == 1 ? a1 : a2)) + bp[lane];
        out[row * 3 + lane] = v;
    }
}

// ---------------- span representations → rep[4096, 2706] ----------------
__global__ __launch_bounds__(256) void span_rep_kernel(
    const float* __restrict__ hidden, const int* __restrict__ spans,
    const float* __restrict__ wemb, float* __restrict__ rep)
{
    int n = blockIdx.x;            // 0..4095
    int b = n >> 9;                // /512
    int s = spans[n * 2 + 0];
    int e = spans[n * 2 + 1];
    int w = e - s + 1;
    const float* hb = hidden + (size_t)b * Sn * Hn;
    float* r = rep + (size_t)n * S_IN_DIM;
    float inv_w = 1.0f / (float)w;

    for (int j = threadIdx.x; j < Hn; j += 256) {
        r[j]      = hb[(size_t)s * Hn + j];
        r[Hn + j] = hb[(size_t)e * Hn + j];
    }
    for (int j = threadIdx.x; j < Hn; j += 256) {
        float acc = 0.f;
        for (int rr = s; rr <= e; ++rr) acc += hb[(size_t)rr * Hn + j];
        r[2 * Hn + j] = acc * inv_w;
    }
    int wi = w > 63 ? 63 : w;
    for (int j = threadIdx.x; j < Hn / 2; j += 256)
        r[3 * Hn + j] = wemb[wi * (Hn / 2) + j];
}

// ---------------- fp32 tiled GEMM, fused bias + exact GELU ----------------
// C[M,N] = act(A[M,lda(:K)] @ Bw[K,N] + bias);  BM=128, BN=64, BK=16
template <bool GELU>
__global__ __launch_bounds__(256) void gemm_bias_act(
    const float* __restrict__ A, int lda,
    const float* __restrict__ Bw, const float* __restrict__ bias,
    float* __restrict__ C, int M, int N, int K)
{
    const int BM = 128, BN = 64, BK = 16;
    __shared__ float As[BK][BM + 4];   // row stride 132 floats (16B-aligned)
    __shared__ float Bs[BK][BN + 4];   // row stride 68 floats (16B-aligned)

    int tid = threadIdx.x;
    int tn = tid & 15;                 // 0..15 → 4 cols each
    int tm = tid >> 4;                 // 0..15 → 8 rows each
    int m0 = blockIdx.x * BM;
    int n0 = blockIdx.y * BN;

    int arow = tid >> 1, akp = (tid & 1) * 8;    // A-load: 8 consecutive k of one row
    int bkr  = tid >> 4, bnc = (tid & 15) * 4;   // B-load: float4 along n

    float acc[8][4] = {};

    for (int k0 = 0; k0 < K; k0 += BK) {
        {
            const float* src = A + (size_t)(m0 + arow) * lda + k0 + akp;
#pragma unroll
            for (int j = 0; j < 8; ++j) {
                int k = k0 + akp + j;
                As[akp + j][arow] = (k < K) ? src[j] : 0.f;
            }
        }
        {
            int k = k0 + bkr;
            float4 v = make_float4(0.f, 0.f, 0.f, 0.f);
            if (k < K) v = *(const float4*)(Bw + (size_t)k * N + n0 + bnc);
            *(float4*)&Bs[bkr][bnc] = v;
        }
        __syncthreads();
#pragma unroll
        for (int kk = 0; kk < BK; ++kk) {
            float4 b4 = *(const float4*)&Bs[kk][tn * 4];
            float4 x0 = *(const float4*)&As[kk][tm * 8];
            float4 x1 = *(const float4*)&As[kk][tm * 8 + 4];
            float av[8] = {x0.x, x0.y, x0.z, x0.w, x1.x, x1.y, x1.z, x1.w};
#pragma unroll
            for (int i = 0; i < 8; ++i) {
                acc[i][0] += av[i] * b4.x;
                acc[i][1] += av[i] * b4.y;
                acc[i][2] += av[i] * b4.z;
                acc[i][3] += av[i] * b4.w;
            }
        }
        __syncthreads();
    }

    float4 bb = *(const float4*)(bias + n0 + tn * 4);
#pragma unroll
    for (int i = 0; i < 8; ++i) {
        int m = m0 + tm * 8 + i;
        float4 v;
        v.x = acc[i][0] + bb.x;
        v.y = acc[i][1] + bb.y;
        v.z = acc[i][2] + bb.z;
        v.w = acc[i][3] + bb.w;
        if (GELU) {
            v.x = 0.5f * v.x * (1.f + erff(v.x * 0.70710678118654752f));
            v.y = 0.5f * v.y * (1.f + erff(v.y * 0.70710678118654752f));
            v.z = 0.5f * v.z * (1.f + erff(v.z * 0.70710678118654752f));
            v.w = 0.5f * v.w * (1.f + erff(v.w * 0.70710678118654752f));
        }
        *(float4*)(C + (size_t)m * N + n0 + tn * 4) = v;
    }
}

// ------- type head: logits = t @ W_t2 + b; softmax → rep[:,2688:2706] -------
__global__ __launch_bounds__(64) void type_head_kernel(
    const float* __restrict__ t, const float* __restrict__ W2,
    const float* __restrict__ b2, float* __restrict__ logits_out,
    float* __restrict__ rep)
{
    int row = blockIdx.x;
    int lane = threadIdx.x;
    const float* tr = t + (size_t)row * Hn;
    float acc[NTYPE] = {};
#pragma unroll
    for (int i = 0; i < Hn / 64; ++i) {
        int k = lane + i * 64;
        float tv = tr[k];
        const float* wk = W2 + k * NTYPE;
#pragma unroll
        for (int o = 0; o < NTYPE; ++o) acc[o] += tv * wk[o];
    }
#pragma unroll
    for (int o = 0; o < NTYPE; ++o)
#pragma unroll
        for (int off = 32; off; off >>= 1) acc[o] += __shfl_xor(acc[o], off);

    float mx = -1e30f;
#pragma unroll
    for (int o = 0; o < NTYPE; ++o) { acc[o] += b2[o]; mx = fmaxf(mx, acc[o]); }
    float p[NTYPE];
    float sum = 0.f;
#pragma unroll
    for (int o = 0; o < NTYPE; ++o) { p[o] = expf(acc[o] - mx); sum += p[o]; }
    float inv = 1.f / sum;
    if (lane < NTYPE) {
        logits_out[row * NTYPE + lane] = acc[lane];
        rep[(size_t)row * S_IN_DIM + SPAN_DIM + lane] = p[lane] * inv;
    }
}

// ---------------- sensitivity head: s @ W_s2 + b ----------------
__global__ __launch_bounds__(64) void sens_head_kernel(
    const float* __restrict__ s, const float* __restrict__ W2,
    const float* __restrict__ b2, float* __restrict__ out)
{
    int row = blockIdx.x;
    int lane = threadIdx.x;
    const float* sr = s + (size_t)row * Hn;
    float acc[NSENS] = {};
#pragma unroll
    for (int i = 0; i < Hn / 64; ++i) {
        int k = lane + i * 64;
        float sv = sr[k];
        const float* wk = W2 + k * NSENS;
#pragma unroll
        for (int o = 0; o < NSENS; ++o) acc[o] += sv * wk[o];
    }
#pragma unroll
    for (int o = 0; o < NSENS; ++o)
#pragma unroll
        for (int off = 32; off; off >>= 1) acc[o] += __shfl_xor(acc[o], off);
    if (lane < NSENS) out[row * NSENS + lane] = acc[lane] + b2[lane];
}

extern "C" void kernel_launch(void* const* d_in, const int* in_sizes, int n_in,
                              void* d_out, int out_size, void* d_ws, size_t ws_size,
                              hipStream_t stream)
{
    const float* hidden = (const float*)d_in[0];
    const int*   spans  = (const int*)d_in[1];
    const float* wemb   = (const float*)d_in[2];
    const float* Wp     = (const float*)d_in[3];
    const float* bp     = (const float*)d_in[4];
    const float* Wt1    = (const float*)d_in[5];
    const float* bt1    = (const float*)d_in[6];
    const float* Wt2    = (const float*)d_in[7];
    const float* bt2    = (const float*)d_in[8];
    const float* Ws1    = (const float*)d_in[9];
    const float* bs1    = (const float*)d_in[10];
    const float* Ws2    = (const float*)d_in[11];
    const float* bs2    = (const float*)d_in[12];

    float* out       = (float*)d_out;
    float* out_prop  = out;                          // 16384*3
    float* out_type  = out + Bn * Sn * 3;            // 4096*18
    float* out_sens  = out_type + NROW * NTYPE;      // 4096*4

    float* rep  = (float*)d_ws;                      // [4096, 2706]
    float* tbuf = rep  + (size_t)NROW * S_IN_DIM;    // [4096, 768]
    float* sbuf = tbuf + (size_t)NROW * Hn;          // [4096, 768]

    proposal_kernel<<<Bn * Sn / 4, 256, 0, stream>>>(hidden, Wp, bp, out_prop);
    span_rep_kernel<<<NROW, 256, 0, stream>>>(hidden, spans, wemb, rep);

    dim3 g1(NROW / 128, Hn / 64);
    gemm_bias_act<true><<<g1, 256, 0, stream>>>(rep, S_IN_DIM, Wt1, bt1, tbuf,
                                                NROW, Hn, SPAN_DIM);
    type_head_kernel<<<NROW, 64, 0, stream>>>(tbuf, Wt2, bt2, out_type, rep);
    gemm_bias_act<true><<<g1, 256, 0, stream>>>(rep, S_IN_DIM, Ws1, bs1, sbuf,
                                                NROW, Hn, S_IN_DIM);
    sens_head_kernel<<<NROW, 64, 0, stream>>>(sbuf, Ws2, bs2, out_sens);
}

// Round 2
// 349.719 us; speedup vs baseline: 3.3200x; 3.3200x over previous
//
#include <hip/hip_runtime.h>
#include <hip/hip_bf16.h>
#include <math.h>

#define Bn 8
#define Sn 2048
#define Hn 768
#define NROW 4096          // B * N_SPANS
#define SPAN_DIM 2688
#define S_IN_DIM 2706
#define KPAD 2720          // padded K for GEMM2 (multiple of 32)
#define NTYPE 18
#define NSENS 4

typedef __attribute__((ext_vector_type(8))) short short8;
typedef __attribute__((ext_vector_type(4))) float floatx4;

__device__ __forceinline__ unsigned short f2bf(float x) {
    __hip_bfloat16 h = __float2bfloat16(x);
    return *reinterpret_cast<unsigned short*>(&h);
}

// ---------------- proposal head: [16384,768] @ [768,3] + b ----------------
__global__ __launch_bounds__(256) void proposal_kernel(
    const float* __restrict__ hidden, const float* __restrict__ Wp,
    const float* __restrict__ bp, float* __restrict__ out)
{
    int wave = threadIdx.x >> 6;
    int lane = threadIdx.x & 63;
    int row  = blockIdx.x * 4 + wave;
    const float* hrow = hidden + (size_t)row * Hn;
    float a0 = 0.f, a1 = 0.f, a2 = 0.f;
#pragma unroll
    for (int i = 0; i < Hn / 64; ++i) {
        int k = lane + i * 64;
        float h = hrow[k];
        a0 += h * Wp[k * 3 + 0];
        a1 += h * Wp[k * 3 + 1];
        a2 += h * Wp[k * 3 + 2];
    }
#pragma unroll
    for (int off = 32; off; off >>= 1) {
        a0 += __shfl_xor(a0, off);
        a1 += __shfl_xor(a1, off);
        a2 += __shfl_xor(a2, off);
    }
    if (lane < 3) {
        float v = (lane == 0 ? a0 : (lane == 1 ? a1 : a2)) + bp[lane];
        out[row * 3 + lane] = v;
    }
}

// ------- span representations → rep[4096, KPAD] bf16 (pad cols zeroed) -------
__global__ __launch_bounds__(256) void span_rep_kernel(
    const float* __restrict__ hidden, const int* __restrict__ spans,
    const float* __restrict__ wemb, unsigned short* __restrict__ rep)
{
    int n = blockIdx.x;
    int b = n >> 9;
    int s = spans[n * 2 + 0];
    int e = spans[n * 2 + 1];
    int w = e - s + 1;
    const float* hb = hidden + (size_t)b * Sn * Hn;
    unsigned short* r = rep + (size_t)n * KPAD;
    float inv_w = 1.0f / (float)w;

    for (int j = threadIdx.x; j < Hn; j += 256) {
        r[j]      = f2bf(hb[(size_t)s * Hn + j]);
        r[Hn + j] = f2bf(hb[(size_t)e * Hn + j]);
    }
    for (int j = threadIdx.x; j < Hn; j += 256) {
        float acc = 0.f;
        for (int rr = s; rr <= e; ++rr) acc += hb[(size_t)rr * Hn + j];
        r[2 * Hn + j] = f2bf(acc * inv_w);
    }
    int wi = w > 63 ? 63 : w;
    for (int j = threadIdx.x; j < Hn / 2; j += 256)
        r[3 * Hn + j] = f2bf(wemb[wi * (Hn / 2) + j]);
    // zero the K padding (cols S_IN_DIM..KPAD-1); prob cols filled later
    for (int j = threadIdx.x; j < KPAD - S_IN_DIM; j += 256)
        r[S_IN_DIM + j] = 0;
}

// ----- weight convert+transpose: W[Kin][N] fp32 -> Wt[N][ldt] bf16 (K zero-pad) -----
__global__ __launch_bounds__(256) void transpose_cvt(
    const float* __restrict__ W, unsigned short* __restrict__ Wt,
    int Kin, int N, int ldt)
{
    __shared__ float tile[32][33];
    int k0 = blockIdx.x * 32;
    int n0 = blockIdx.y * 32;
    int tx = threadIdx.x & 31, ty = threadIdx.x >> 5;  // ty 0..7
#pragma unroll
    for (int i = 0; i < 32; i += 8) {
        int k = k0 + ty + i;
        tile[ty + i][tx] = (k < Kin) ? W[(size_t)k * N + n0 + tx] : 0.f;
    }
    __syncthreads();
#pragma unroll
    for (int i = 0; i < 32; i += 8) {
        int nn = n0 + ty + i;
        Wt[(size_t)nn * ldt + k0 + tx] = f2bf(tile[tx][ty + i]);
    }
}

// ---------------- bf16 MFMA GEMM: C[M,N] = act(A @ Bt^T + bias) ----------------
// A: [M][lda] bf16 row-major (K used); Bt: [N][ldb] bf16 (weights pre-transposed)
// 128x128 block tile, BK=32, 4 waves each 64x64 via 4x4 of 16x16x32 MFMA.
template <bool GELU>
__global__ __launch_bounds__(256) void gemm_mfma(
    const unsigned short* __restrict__ A, int lda,
    const unsigned short* __restrict__ Bt, int ldb,
    const float* __restrict__ bias,
    float* __restrict__ C, int ldc, int K)
{
    const int BK = 32, PAD = 8;
    __shared__ unsigned short As[128][BK + PAD];
    __shared__ unsigned short Bs[128][BK + PAD];

    int tid  = threadIdx.x;
    int wave = tid >> 6, lane = tid & 63;
    int wr = (wave >> 1) * 64;
    int wc = (wave & 1) * 64;
    int m0 = blockIdx.x * 128;
    int n0 = blockIdx.y * 128;

    int ls_row = tid >> 2;         // 0..63
    int ls_col = (tid & 3) * 8;    // 0,8,16,24

    int fr = lane & 15;            // row/col within 16x16 frag
    int fq = (lane >> 4) * 8;      // k offset within BK

    floatx4 acc[4][4] = {};

    const unsigned short* Aptr = A + (size_t)m0 * lda;
    const unsigned short* Bptr = Bt + (size_t)n0 * ldb;

    for (int k0 = 0; k0 < K; k0 += BK) {
        *(float4*)&As[ls_row][ls_col] =
            *(const float4*)(Aptr + (size_t)ls_row * lda + k0 + ls_col);
        *(float4*)&As[ls_row + 64][ls_col] =
            *(const float4*)(Aptr + (size_t)(ls_row + 64) * lda + k0 + ls_col);
        *(float4*)&Bs[ls_row][ls_col] =
            *(const float4*)(Bptr + (size_t)ls_row * ldb + k0 + ls_col);
        *(float4*)&Bs[ls_row + 64][ls_col] =
            *(const float4*)(Bptr + (size_t)(ls_row + 64) * ldb + k0 + ls_col);
        __syncthreads();

        short8 af[4], bf[4];
#pragma unroll
        for (int i = 0; i < 4; ++i) {
            af[i] = *(const short8*)&As[wr + i * 16 + fr][fq];
            bf[i] = *(const short8*)&Bs[wc + i * 16 + fr][fq];
        }
#pragma unroll
        for (int mi = 0; mi < 4; ++mi)
#pragma unroll
            for (int ni = 0; ni < 4; ++ni)
                acc[mi][ni] = __builtin_amdgcn_mfma_f32_16x16x32_bf16(
                    af[mi], bf[ni], acc[mi][ni], 0, 0, 0);
        __syncthreads();
    }

    // C/D layout: col = lane&15, row = (lane>>4)*4 + reg
    int cr = (lane >> 4) * 4;
#pragma unroll
    for (int mi = 0; mi < 4; ++mi) {
#pragma unroll
        for (int ni = 0; ni < 4; ++ni) {
            int col = n0 + wc + ni * 16 + fr;
            float bv = bias[col];
#pragma unroll
            for (int r = 0; r < 4; ++r) {
                int row = m0 + wr + mi * 16 + cr + r;
                float v = acc[mi][ni][r] + bv;
                if (GELU) v = 0.5f * v * (1.f + erff(v * 0.70710678118654752f));
                C[(size_t)row * ldc + col] = v;
            }
        }
    }
}

// ------- type head: logits = t @ W_t2 + b; softmax → rep[:,2688:2706] bf16 -------
__global__ __launch_bounds__(64) void type_head_kernel(
    const float* __restrict__ t, const float* __restrict__ W2,
    const float* __restrict__ b2, float* __restrict__ logits_out,
    unsigned short* __restrict__ rep)
{
    int row = blockIdx.x;
    int lane = threadIdx.x;
    const float* tr = t + (size_t)row * Hn;
    float acc[NTYPE] = {};
#pragma unroll
    for (int i = 0; i < Hn / 64; ++i) {
        int k = lane + i * 64;
        float tv = tr[k];
        const float* wk = W2 + k * NTYPE;
#pragma unroll
        for (int o = 0; o < NTYPE; ++o) acc[o] += tv * wk[o];
    }
#pragma unroll
    for (int o = 0; o < NTYPE; ++o)
#pragma unroll
        for (int off = 32; off; off >>= 1) acc[o] += __shfl_xor(acc[o], off);

    float mx = -1e30f;
#pragma unroll
    for (int o = 0; o < NTYPE; ++o) { acc[o] += b2[o]; mx = fmaxf(mx, acc[o]); }
    float p[NTYPE];
    float sum = 0.f;
#pragma unroll
    for (int o = 0; o < NTYPE; ++o) { p[o] = expf(acc[o] - mx); sum += p[o]; }
    float inv = 1.f / sum;
    if (lane < NTYPE) {
        logits_out[row * NTYPE + lane] = acc[lane];
        rep[(size_t)row * KPAD + SPAN_DIM + lane] = f2bf(p[lane] * inv);
    }
}

// ---------------- sensitivity head: s @ W_s2 + b ----------------
__global__ __launch_bounds__(64) void sens_head_kernel(
    const float* __restrict__ s, const float* __restrict__ W2,
    const float* __restrict__ b2, float* __restrict__ out)
{
    int row = blockIdx.x;
    int lane = threadIdx.x;
    const float* sr = s + (size_t)row * Hn;
    float acc[NSENS] = {};
#pragma unroll
    for (int i = 0; i < Hn / 64; ++i) {
        int k = lane + i * 64;
        float sv = sr[k];
        const float* wk = W2 + k * NSENS;
#pragma unroll
        for (int o = 0; o < NSENS; ++o) acc[o] += sv * wk[o];
    }
#pragma unroll
    for (int o = 0; o < NSENS; ++o)
#pragma unroll
        for (int off = 32; off; off >>= 1) acc[o] += __shfl_xor(acc[o], off);
    if (lane < NSENS) out[row * NSENS + lane] = acc[lane] + b2[lane];
}

extern "C" void kernel_launch(void* const* d_in, const int* in_sizes, int n_in,
                              void* d_out, int out_size, void* d_ws, size_t ws_size,
                              hipStream_t stream)
{
    const float* hidden = (const float*)d_in[0];
    const int*   spans  = (const int*)d_in[1];
    const float* wemb   = (const float*)d_in[2];
    const float* Wp     = (const float*)d_in[3];
    const float* bp     = (const float*)d_in[4];
    const float* Wt1    = (const float*)d_in[5];
    const float* bt1    = (const float*)d_in[6];
    const float* Wt2    = (const float*)d_in[7];
    const float* bt2    = (const float*)d_in[8];
    const float* Ws1    = (const float*)d_in[9];
    const float* bs1    = (const float*)d_in[10];
    const float* Ws2    = (const float*)d_in[11];
    const float* bs2    = (const float*)d_in[12];

    float* out      = (float*)d_out;
    float* out_prop = out;
    float* out_type = out + Bn * Sn * 3;
    float* out_sens = out_type + NROW * NTYPE;

    // workspace layout (16B-aligned chunks)
    unsigned short* rep  = (unsigned short*)d_ws;               // [4096][2720] bf16
    float* tbuf = (float*)(rep + (size_t)NROW * KPAD);          // [4096][768] fp32
    float* sbuf = tbuf + (size_t)NROW * Hn;                     // [4096][768] fp32
    unsigned short* WT1t = (unsigned short*)(sbuf + (size_t)NROW * Hn); // [768][2688]
    unsigned short* WS1t = WT1t + (size_t)Hn * SPAN_DIM;        // [768][2720]

    // weight prep (cheap, once per launch)
    transpose_cvt<<<dim3(SPAN_DIM / 32, Hn / 32), 256, 0, stream>>>(
        Wt1, WT1t, SPAN_DIM, Hn, SPAN_DIM);
    transpose_cvt<<<dim3(KPAD / 32, Hn / 32), 256, 0, stream>>>(
        Ws1, WS1t, S_IN_DIM, Hn, KPAD);

    proposal_kernel<<<Bn * Sn / 4, 256, 0, stream>>>(hidden, Wp, bp, out_prop);
    span_rep_kernel<<<NROW, 256, 0, stream>>>(hidden, spans, wemb, rep);

    dim3 gg(NROW / 128, Hn / 128);
    gemm_mfma<true><<<gg, 256, 0, stream>>>(rep, KPAD, WT1t, SPAN_DIM, bt1,
                                            tbuf, Hn, SPAN_DIM);
    type_head_kernel<<<NROW, 64, 0, stream>>>(tbuf, Wt2, bt2, out_type, rep);
    gemm_mfma<true><<<gg, 256, 0, stream>>>(rep, KPAD, WS1t, KPAD, bs1,
                                            sbuf, Hn, KPAD);
    sens_head_kernel<<<NROW, 64, 0, stream>>>(sbuf, Ws2, bs2, out_sens);
}

// Round 3
// 241.780 us; speedup vs baseline: 4.8021x; 1.4464x over previous
//
#include <hip/hip_runtime.h>
#include <hip/hip_bf16.h>
#include <math.h>

#define Bn 8
#define Sn 2048
#define Hn 768
#define NROW 4096          // B * N_SPANS
#define SPAN_DIM 2688
#define NBIG 1536          // fused GEMM N (768 type-t | 768 sens-pre)
#define NTYPE 18
#define NSENS 4

typedef __attribute__((ext_vector_type(8))) short short8;
typedef __attribute__((ext_vector_type(4))) float floatx4;

__device__ __forceinline__ unsigned short f2bf(float x) {
    __hip_bfloat16 h = __float2bfloat16(x);
    return *reinterpret_cast<unsigned short*>(&h);
}

__device__ __forceinline__ void glds16(const void* g, void* l) {
    __builtin_amdgcn_global_load_lds(
        (const __attribute__((address_space(1))) unsigned int*)g,
        (__attribute__((address_space(3))) unsigned int*)l, 16, 0, 0);
}

__device__ __forceinline__ float gelu_exact(float v) {
    return 0.5f * v * (1.f + erff(v * 0.70710678118654752f));
}

// ---------------- proposal head: [16384,768] @ [768,3] + b ----------------
__global__ __launch_bounds__(256) void proposal_kernel(
    const float* __restrict__ hidden, const float* __restrict__ Wp,
    const float* __restrict__ bp, float* __restrict__ out)
{
    int wave = threadIdx.x >> 6;
    int lane = threadIdx.x & 63;
    int row  = blockIdx.x * 4 + wave;
    const float4* h4 = (const float4*)(hidden + (size_t)row * Hn);
    float a0 = 0.f, a1 = 0.f, a2 = 0.f;
#pragma unroll
    for (int i = 0; i < 3; ++i) {
        int kc = i * 64 + lane;           // float4 chunk, k = kc*4
        float4 h = h4[kc];
        const float* w = Wp + kc * 12;
        a0 += h.x * w[0] + h.y * w[3] + h.z * w[6] + h.w * w[9];
        a1 += h.x * w[1] + h.y * w[4] + h.z * w[7] + h.w * w[10];
        a2 += h.x * w[2] + h.y * w[5] + h.z * w[8] + h.w * w[11];
    }
#pragma unroll
    for (int off = 32; off; off >>= 1) {
        a0 += __shfl_xor(a0, off);
        a1 += __shfl_xor(a1, off);
        a2 += __shfl_xor(a2, off);
    }
    if (lane < 3) {
        float v = (lane == 0 ? a0 : (lane == 1 ? a1 : a2)) + bp[lane];
        out[row * 3 + lane] = v;
    }
}

// ------- span representations → rep[4096, 2688] bf16, vectorized -------
__global__ __launch_bounds__(192) void span_rep_kernel(
    const float* __restrict__ hidden, const int* __restrict__ spans,
    const float* __restrict__ wemb, unsigned short* __restrict__ rep)
{
    int n = blockIdx.x;
    int b = n >> 9;
    int s = spans[n * 2 + 0];
    int e = spans[n * 2 + 1];
    int w = e - s + 1;
    const float4* hb4 = (const float4*)(hidden + (size_t)b * Sn * Hn);
    unsigned short* r = rep + (size_t)n * SPAN_DIM;
    float inv_w = 1.0f / (float)w;
    int tid = threadIdx.x;                // 0..191, one float4 chunk each

    float4 sv = hb4[(size_t)s * 192 + tid];
    float4 ev = hb4[(size_t)e * 192 + tid];
    float4 pv = make_float4(0.f, 0.f, 0.f, 0.f);
    for (int rr = s; rr <= e; ++rr) {
        float4 h = hb4[(size_t)rr * 192 + tid];
        pv.x += h.x; pv.y += h.y; pv.z += h.z; pv.w += h.w;
    }
    pv.x *= inv_w; pv.y *= inv_w; pv.z *= inv_w; pv.w *= inv_w;

    *(ushort4*)&r[tid * 4] =
        make_ushort4(f2bf(sv.x), f2bf(sv.y), f2bf(sv.z), f2bf(sv.w));
    *(ushort4*)&r[Hn + tid * 4] =
        make_ushort4(f2bf(ev.x), f2bf(ev.y), f2bf(ev.z), f2bf(ev.w));
    *(ushort4*)&r[2 * Hn + tid * 4] =
        make_ushort4(f2bf(pv.x), f2bf(pv.y), f2bf(pv.z), f2bf(pv.w));
    if (tid < 96) {
        int wi = w > 63 ? 63 : w;
        float4 wv = ((const float4*)wemb)[wi * 96 + tid];
        *(ushort4*)&r[3 * Hn + tid * 4] =
            make_ushort4(f2bf(wv.x), f2bf(wv.y), f2bf(wv.z), f2bf(wv.w));
    }
}

// ----- weight convert+transpose: W[Kin][N] fp32 -> Wt[N][ldt] bf16 -----
__global__ __launch_bounds__(256) void transpose_cvt(
    const float* __restrict__ W, unsigned short* __restrict__ Wt,
    int Kin, int N, int ldt)
{
    __shared__ float tile[32][33];
    int k0 = blockIdx.x * 32;
    int n0 = blockIdx.y * 32;
    int tx = threadIdx.x & 31, ty = threadIdx.x >> 5;
#pragma unroll
    for (int i = 0; i < 32; i += 8) {
        int k = k0 + ty + i;
        tile[ty + i][tx] = (k < Kin) ? W[(size_t)k * N + n0 + tx] : 0.f;
    }
    __syncthreads();
#pragma unroll
    for (int i = 0; i < 32; i += 8) {
        int nn = n0 + ty + i;
        Wt[(size_t)nn * ldt + k0 + tx] = f2bf(tile[tx][ty + i]);
    }
}

// ------------- fused bf16 MFMA GEMM: obuf = epilogue(rep @ WbigT^T) -------------
// A: [4096][2688] bf16; Bt: [1536][2688] bf16. 128x64 tile, BK=32, 4 waves.
// Staging via global_load_lds(16B) into XOR-swizzled LDS (chunk slot = r*4 + (c^((r>>1)&3))).
__global__ __launch_bounds__(256, 3) void gemm_fused(
    const unsigned short* __restrict__ A,
    const unsigned short* __restrict__ Bt,
    const float* __restrict__ bt1, const float* __restrict__ bs1,
    float* __restrict__ obuf)
{
    const int BM = 128, BN = 64, BK = 32;
    __shared__ unsigned short As[BM * BK];   // 8 KB, swizzled 16B chunks
    __shared__ unsigned short Bs[BN * BK];   // 4 KB

    int tid = threadIdx.x, wave = tid >> 6, lane = tid & 63;
    int m0 = blockIdx.x * BM, n0 = blockIdx.y * BN;

    int wr = (wave >> 1) * 64;      // wave tile 64(m) x 32(n)
    int wc = (wave & 1) * 32;
    int fr = lane & 15;
    int fc = lane >> 4;             // K-chunk index (8 shorts each)

    // staging slots: A: d0=tid, d1=256+tid; B: d=tid. slot -> r=d>>2, c=(d&3)^((r>>1)&3)
    int rA0 = tid >> 2,        cA0 = (tid & 3) ^ ((rA0 >> 1) & 3);
    int dA1 = 256 + tid;
    int rA1 = dA1 >> 2,        cA1 = (dA1 & 3) ^ ((rA1 >> 1) & 3);
    int rB  = tid >> 2,        cB  = (tid & 3) ^ ((rB >> 1) & 3);

    const unsigned short* gA0 = A + (size_t)(m0 + rA0) * SPAN_DIM + cA0 * 8;
    const unsigned short* gA1 = A + (size_t)(m0 + rA1) * SPAN_DIM + cA1 * 8;
    const unsigned short* gB  = Bt + (size_t)(n0 + rB) * SPAN_DIM + cB * 8;

    unsigned short* ldsA0 = As + wave * 512;          // slots wave*64.., 16B each
    unsigned short* ldsA1 = As + 2048 + wave * 512;
    unsigned short* ldsB  = Bs + wave * 512;

    floatx4 acc[4][2] = {};

    for (int k0 = 0; k0 < SPAN_DIM; k0 += BK) {
        glds16(gA0 + k0, ldsA0);
        glds16(gA1 + k0, ldsA1);
        glds16(gB + k0, ldsB);
        __syncthreads();            // drains vmcnt + barrier

        short8 af[4], bf[2];
#pragma unroll
        for (int i = 0; i < 4; ++i) {
            int r = wr + i * 16 + fr;
            af[i] = *(const short8*)&As[(r * 4 + (fc ^ ((r >> 1) & 3))) * 8];
        }
#pragma unroll
        for (int i = 0; i < 2; ++i) {
            int r = wc + i * 16 + fr;
            bf[i] = *(const short8*)&Bs[(r * 4 + (fc ^ ((r >> 1) & 3))) * 8];
        }
#pragma unroll
        for (int mi = 0; mi < 4; ++mi)
#pragma unroll
            for (int ni = 0; ni < 2; ++ni)
                acc[mi][ni] = __builtin_amdgcn_mfma_f32_16x16x32_bf16(
                    af[mi], bf[ni], acc[mi][ni], 0, 0, 0);
        __syncthreads();            // protect LDS before next overwrite
    }

    // epilogue: n0 < 768 -> t half (bias bt1 + GELU); else sens-pre (bias bs1)
    bool isT = (n0 < Hn);
    const float* bias = isT ? bt1 : (bs1 - Hn);
    int cr = (lane >> 4) * 4;
#pragma unroll
    for (int mi = 0; mi < 4; ++mi) {
#pragma unroll
        for (int ni = 0; ni < 2; ++ni) {
            int col = n0 + wc + ni * 16 + fr;
            float bv = bias[col];
#pragma unroll
            for (int r = 0; r < 4; ++r) {
                int row = m0 + wr + mi * 16 + cr + r;
                float v = acc[mi][ni][r] + bv;
                if (isT) v = gelu_exact(v);
                obuf[(size_t)row * NBIG + col] = v;
            }
        }
    }
}

// ------- type head: logits = t @ W_t2 + b; softmax → pbuf fp32 -------
__global__ __launch_bounds__(64) void type_head_kernel(
    const float* __restrict__ obuf, const float* __restrict__ W2,
    const float* __restrict__ b2, float* __restrict__ logits_out,
    float* __restrict__ pbuf)
{
    int row = blockIdx.x;
    int lane = threadIdx.x;
    const float* tr = obuf + (size_t)row * NBIG;     // t half: cols 0..767
    float acc[NTYPE] = {};
#pragma unroll
    for (int i = 0; i < Hn / 64; ++i) {
        int k = lane + i * 64;
        float tv = tr[k];
        const float* wk = W2 + k * NTYPE;
#pragma unroll
        for (int o = 0; o < NTYPE; ++o) acc[o] += tv * wk[o];
    }
#pragma unroll
    for (int o = 0; o < NTYPE; ++o)
#pragma unroll
        for (int off = 32; off; off >>= 1) acc[o] += __shfl_xor(acc[o], off);

    float mx = -1e30f;
#pragma unroll
    for (int o = 0; o < NTYPE; ++o) { acc[o] += b2[o]; mx = fmaxf(mx, acc[o]); }
    float p[NTYPE];
    float sum = 0.f;
#pragma unroll
    for (int o = 0; o < NTYPE; ++o) { p[o] = expf(acc[o] - mx); sum += p[o]; }
    float inv = 1.f / sum;
    if (lane < NTYPE) {
        logits_out[row * NTYPE + lane] = acc[lane];
        pbuf[row * NTYPE + lane] = p[lane] * inv;
    }
}

// --- fused: s = GELU(spre + probs @ Ws1_tail); out = s @ W_s2 + b_s2 ---
__global__ __launch_bounds__(64) void tail_sens_kernel(
    const float* __restrict__ obuf, const float* __restrict__ pbuf,
    const float* __restrict__ Ws1, const float* __restrict__ Ws2,
    const float* __restrict__ bs2, float* __restrict__ out)
{
    int row = blockIdx.x;
    int lane = threadIdx.x;
    const float* sp = obuf + (size_t)row * NBIG + Hn;   // sens-pre half
    float pr[NTYPE];
#pragma unroll
    for (int o = 0; o < NTYPE; ++o) pr[o] = pbuf[row * NTYPE + o];
    float acc[NSENS] = {};
#pragma unroll
    for (int i = 0; i < 12; ++i) {
        int j = lane + i * 64;
        float v = sp[j];
        float t = 0.f;
#pragma unroll
        for (int o = 0; o < NTYPE; ++o)
            t += pr[o] * Ws1[(size_t)(SPAN_DIM + o) * Hn + j];
        v = gelu_exact(v + t);
#pragma unroll
        for (int o = 0; o < NSENS; ++o) acc[o] += v * Ws2[j * NSENS + o];
    }
#pragma unroll
    for (int o = 0; o < NSENS; ++o)
#pragma unroll
        for (int off = 32; off; off >>= 1) acc[o] += __shfl_xor(acc[o], off);
    if (lane < NSENS) out[row * NSENS + lane] = acc[lane] + bs2[lane];
}

extern "C" void kernel_launch(void* const* d_in, const int* in_sizes, int n_in,
                              void* d_out, int out_size, void* d_ws, size_t ws_size,
                              hipStream_t stream)
{
    const float* hidden = (const float*)d_in[0];
    const int*   spans  = (const int*)d_in[1];
    const float* wemb   = (const float*)d_in[2];
    const float* Wp     = (const float*)d_in[3];
    const float* bp     = (const float*)d_in[4];
    const float* Wt1    = (const float*)d_in[5];
    const float* bt1    = (const float*)d_in[6];
    const float* Wt2    = (const float*)d_in[7];
    const float* bt2    = (const float*)d_in[8];
    const float* Ws1    = (const float*)d_in[9];
    const float* bs1    = (const float*)d_in[10];
    const float* Ws2    = (const float*)d_in[11];
    const float* bs2    = (const float*)d_in[12];

    float* out      = (float*)d_out;
    float* out_prop = out;
    float* out_type = out + Bn * Sn * 3;
    float* out_sens = out_type + NROW * NTYPE;

    // workspace layout (all 16B-aligned)
    unsigned short* rep = (unsigned short*)d_ws;                 // [4096][2688] bf16
    float* obuf = (float*)(rep + (size_t)NROW * SPAN_DIM);       // [4096][1536] fp32
    unsigned short* WbigT = (unsigned short*)(obuf + (size_t)NROW * NBIG); // [1536][2688]
    float* pbuf = (float*)(WbigT + (size_t)NBIG * SPAN_DIM);     // [4096][18] fp32

    // weight prep: WbigT rows 0..767 = Wt1^T, rows 768..1535 = Ws1[:2688]^T
    transpose_cvt<<<dim3(SPAN_DIM / 32, Hn / 32), 256, 0, stream>>>(
        Wt1, WbigT, SPAN_DIM, Hn, SPAN_DIM);
    transpose_cvt<<<dim3(SPAN_DIM / 32, Hn / 32), 256, 0, stream>>>(
        Ws1, WbigT + (size_t)Hn * SPAN_DIM, SPAN_DIM, Hn, SPAN_DIM);

    proposal_kernel<<<Bn * Sn / 4, 256, 0, stream>>>(hidden, Wp, bp, out_prop);
    span_rep_kernel<<<NROW, 192, 0, stream>>>(hidden, spans, wemb, rep);

    dim3 gg(NROW / 128, NBIG / 64);   // 32 x 24 = 768 blocks = 3/CU
    gemm_fused<<<gg, 256, 0, stream>>>(rep, WbigT, bt1, bs1, obuf);

    type_head_kernel<<<NROW, 64, 0, stream>>>(obuf, Wt2, bt2, out_type, pbuf);
    tail_sens_kernel<<<NROW, 64, 0, stream>>>(obuf, pbuf, Ws1, Ws2, bs2, out_sens);
}

// Round 4
// 227.259 us; speedup vs baseline: 5.1089x; 1.0639x over previous
//
#include <hip/hip_runtime.h>
#include <hip/hip_bf16.h>
#include <math.h>

#define Bn 8
#define Sn 2048
#define Hn 768
#define NROW 4096          // B * N_SPANS
#define SPAN_DIM 2688
#define NBIG 1536          // fused GEMM N (768 type-t | 768 sens-pre)
#define NTYPE 18
#define NSENS 4

typedef __attribute__((ext_vector_type(8))) short short8;
typedef __attribute__((ext_vector_type(4))) float floatx4;

__device__ __forceinline__ unsigned short f2bf(float x) {
    __hip_bfloat16 h = __float2bfloat16(x);
    return *reinterpret_cast<unsigned short*>(&h);
}

__device__ __forceinline__ void glds16(const void* g, void* l) {
    __builtin_amdgcn_global_load_lds(
        (const __attribute__((address_space(1))) unsigned int*)g,
        (__attribute__((address_space(3))) unsigned int*)l, 16, 0, 0);
}

__device__ __forceinline__ float gelu_exact(float v) {
    return 0.5f * v * (1.f + erff(v * 0.70710678118654752f));
}

// ---------------- proposal head: [16384,768] @ [768,3] + b ----------------
__global__ __launch_bounds__(256) void proposal_kernel(
    const float* __restrict__ hidden, const float* __restrict__ Wp,
    const float* __restrict__ bp, float* __restrict__ out)
{
    int wave = threadIdx.x >> 6;
    int lane = threadIdx.x & 63;
    int row  = blockIdx.x * 4 + wave;
    const float4* h4 = (const float4*)(hidden + (size_t)row * Hn);
    float a0 = 0.f, a1 = 0.f, a2 = 0.f;
#pragma unroll
    for (int i = 0; i < 3; ++i) {
        int kc = i * 64 + lane;
        float4 h = h4[kc];
        const float* w = Wp + kc * 12;
        a0 += h.x * w[0] + h.y * w[3] + h.z * w[6] + h.w * w[9];
        a1 += h.x * w[1] + h.y * w[4] + h.z * w[7] + h.w * w[10];
        a2 += h.x * w[2] + h.y * w[5] + h.z * w[8] + h.w * w[11];
    }
#pragma unroll
    for (int off = 32; off; off >>= 1) {
        a0 += __shfl_xor(a0, off);
        a1 += __shfl_xor(a1, off);
        a2 += __shfl_xor(a2, off);
    }
    if (lane < 3) {
        float v = (lane == 0 ? a0 : (lane == 1 ? a1 : a2)) + bp[lane];
        out[row * 3 + lane] = v;
    }
}

// ------- span representations → rep[4096, 2688] bf16, unroll-4 pooling -------
__global__ __launch_bounds__(192) void span_rep_kernel(
    const float* __restrict__ hidden, const int* __restrict__ spans,
    const float* __restrict__ wemb, unsigned short* __restrict__ rep)
{
    int n = blockIdx.x;
    int b = n >> 9;
    int s = spans[n * 2 + 0];
    int e = spans[n * 2 + 1];
    int w = e - s + 1;
    const float4* hb4 = (const float4*)(hidden + (size_t)b * Sn * Hn);
    unsigned short* r = rep + (size_t)n * SPAN_DIM;
    float inv_w = 1.0f / (float)w;
    int tid = threadIdx.x;

    float4 sv = hb4[(size_t)s * 192 + tid];
    float4 ev = hb4[(size_t)e * 192 + tid];
    float4 p0 = make_float4(0.f, 0.f, 0.f, 0.f), p1 = p0, p2 = p0, p3 = p0;
    int rr = s;
    for (; rr + 3 <= e; rr += 4) {
        float4 h0 = hb4[(size_t)(rr + 0) * 192 + tid];
        float4 h1 = hb4[(size_t)(rr + 1) * 192 + tid];
        float4 h2 = hb4[(size_t)(rr + 2) * 192 + tid];
        float4 h3 = hb4[(size_t)(rr + 3) * 192 + tid];
        p0.x += h0.x; p0.y += h0.y; p0.z += h0.z; p0.w += h0.w;
        p1.x += h1.x; p1.y += h1.y; p1.z += h1.z; p1.w += h1.w;
        p2.x += h2.x; p2.y += h2.y; p2.z += h2.z; p2.w += h2.w;
        p3.x += h3.x; p3.y += h3.y; p3.z += h3.z; p3.w += h3.w;
    }
    for (; rr <= e; ++rr) {
        float4 h = hb4[(size_t)rr * 192 + tid];
        p0.x += h.x; p0.y += h.y; p0.z += h.z; p0.w += h.w;
    }
    float4 pv;
    pv.x = ((p0.x + p1.x) + (p2.x + p3.x)) * inv_w;
    pv.y = ((p0.y + p1.y) + (p2.y + p3.y)) * inv_w;
    pv.z = ((p0.z + p1.z) + (p2.z + p3.z)) * inv_w;
    pv.w = ((p0.w + p1.w) + (p2.w + p3.w)) * inv_w;

    *(ushort4*)&r[tid * 4] =
        make_ushort4(f2bf(sv.x), f2bf(sv.y), f2bf(sv.z), f2bf(sv.w));
    *(ushort4*)&r[Hn + tid * 4] =
        make_ushort4(f2bf(ev.x), f2bf(ev.y), f2bf(ev.z), f2bf(ev.w));
    *(ushort4*)&r[2 * Hn + tid * 4] =
        make_ushort4(f2bf(pv.x), f2bf(pv.y), f2bf(pv.z), f2bf(pv.w));
    if (tid < 96) {
        int wi = w > 63 ? 63 : w;
        float4 wv = ((const float4*)wemb)[wi * 96 + tid];
        *(ushort4*)&r[3 * Hn + tid * 4] =
            make_ushort4(f2bf(wv.x), f2bf(wv.y), f2bf(wv.z), f2bf(wv.w));
    }
}

// ----- weight prep: z=0/1 big transposes -> WbigT bf16; z=2 small transposes -----
__global__ __launch_bounds__(256) void prep_weights(
    const float* __restrict__ Wt1, const float* __restrict__ Ws1,
    unsigned short* __restrict__ WbigT,
    const float* __restrict__ Wt2, const float* __restrict__ Ws2,
    float* __restrict__ Wt2t, float* __restrict__ Ws2t)
{
    int z = blockIdx.z;
    if (z == 2) {
        int gid = blockIdx.y * 84 + blockIdx.x;
        int idx = gid * 256 + threadIdx.x;
        if (idx < Hn * NTYPE) {
            int o = idx / Hn, c = idx - o * Hn;
            Wt2t[idx] = Wt2[c * NTYPE + o];
        } else if (idx < Hn * (NTYPE + NSENS)) {
            int j = idx - Hn * NTYPE;
            int o = j / Hn, c = j - o * Hn;
            Ws2t[j] = Ws2[c * NSENS + o];
        }
        return;
    }
    const float* W = (z == 0) ? Wt1 : Ws1;
    unsigned short* Wt = WbigT + (size_t)z * Hn * SPAN_DIM;
    __shared__ float tile[32][33];
    int k0 = blockIdx.x * 32, n0 = blockIdx.y * 32;
    int tx = threadIdx.x & 31, ty = threadIdx.x >> 5;
#pragma unroll
    for (int i = 0; i < 32; i += 8)
        tile[ty + i][tx] = W[(size_t)(k0 + ty + i) * Hn + n0 + tx];
    __syncthreads();
#pragma unroll
    for (int i = 0; i < 32; i += 8)
        Wt[(size_t)(n0 + ty + i) * SPAN_DIM + k0 + tx] = f2bf(tile[tx][ty + i]);
}

// ------------- fused bf16 MFMA GEMM: obuf = epilogue(rep @ WbigT^T) -------------
// 128x64 block tile, BK=64, 4 waves (each 64x32). Swizzled glds16 staging.
__global__ __launch_bounds__(256, 3) void gemm_fused(
    const unsigned short* __restrict__ A,
    const unsigned short* __restrict__ Bt,
    const float* __restrict__ bt1, const float* __restrict__ bs1,
    float* __restrict__ obuf)
{
    const int BK = 64;
    __shared__ unsigned short As[128 * BK];   // 16 KB
    __shared__ unsigned short Bs[64 * BK];    // 8 KB

    int tid = threadIdx.x, wave = tid >> 6, lane = tid & 63;
    int m0 = blockIdx.x * 128, n0 = blockIdx.y * 64;
    int wr = (wave >> 1) * 64;
    int wc = (wave & 1) * 32;
    int fr = lane & 15;
    int fc = lane >> 4;             // 0..3

    const unsigned short* gA[4];
#pragma unroll
    for (int j = 0; j < 4; ++j) {
        int d = tid + j * 256;
        int r = d >> 3, c = (d & 7) ^ (r & 7);
        gA[j] = A + (size_t)(m0 + r) * SPAN_DIM + c * 8;
    }
    const unsigned short* gB[2];
#pragma unroll
    for (int j = 0; j < 2; ++j) {
        int d = tid + j * 256;
        int r = d >> 3, c = (d & 7) ^ (r & 7);
        gB[j] = Bt + (size_t)(n0 + r) * SPAN_DIM + c * 8;
    }
    unsigned short* ldsA[4];
    unsigned short* ldsB[2];
#pragma unroll
    for (int j = 0; j < 4; ++j) ldsA[j] = As + j * 2048 + wave * 512;
#pragma unroll
    for (int j = 0; j < 2; ++j) ldsB[j] = Bs + j * 2048 + wave * 512;

    floatx4 acc[4][2] = {};

    for (int k0 = 0; k0 < SPAN_DIM; k0 += BK) {
        glds16(gA[0] + k0, ldsA[0]);
        glds16(gA[1] + k0, ldsA[1]);
        glds16(gA[2] + k0, ldsA[2]);
        glds16(gA[3] + k0, ldsA[3]);
        glds16(gB[0] + k0, ldsB[0]);
        glds16(gB[1] + k0, ldsB[1]);
        __syncthreads();

#pragma unroll
        for (int half = 0; half < 2; ++half) {
            int cb = half * 4 + fc;
            short8 af[4], bf[2];
#pragma unroll
            for (int i = 0; i < 4; ++i) {
                int r = wr + i * 16 + fr;
                af[i] = *(const short8*)&As[((r << 3) | (cb ^ (r & 7))) * 8];
            }
#pragma unroll
            for (int i = 0; i < 2; ++i) {
                int r = wc + i * 16 + fr;
                bf[i] = *(const short8*)&Bs[((r << 3) | (cb ^ (r & 7))) * 8];
            }
#pragma unroll
            for (int mi = 0; mi < 4; ++mi)
#pragma unroll
                for (int ni = 0; ni < 2; ++ni)
                    acc[mi][ni] = __builtin_amdgcn_mfma_f32_16x16x32_bf16(
                        af[mi], bf[ni], acc[mi][ni], 0, 0, 0);
        }
        __syncthreads();
    }

    bool isT = (n0 < Hn);
    const float* bias = isT ? bt1 : (bs1 - Hn);
    int cr = (lane >> 4) * 4;
#pragma unroll
    for (int mi = 0; mi < 4; ++mi) {
#pragma unroll
        for (int ni = 0; ni < 2; ++ni) {
            int col = n0 + wc + ni * 16 + fr;
            float bv = bias[col];
#pragma unroll
            for (int r = 0; r < 4; ++r) {
                int row = m0 + wr + mi * 16 + cr + r;
                float v = acc[mi][ni][r] + bv;
                if (isT) v = gelu_exact(v);
                obuf[(size_t)row * NBIG + col] = v;
            }
        }
    }
}

// --- fused heads: type logits + softmax + tail-correction + GELU + sens head ---
// one 64-lane wave per row, 4 rows per block, no cross-wave sync
__global__ __launch_bounds__(256) void heads_kernel(
    const float* __restrict__ obuf, const float* __restrict__ Wt2t,
    const float* __restrict__ bt2, const float* __restrict__ Ws1,
    const float* __restrict__ Ws2t, const float* __restrict__ bs2,
    float* __restrict__ out_type, float* __restrict__ out_sens)
{
    int wave = threadIdx.x >> 6, lane = threadIdx.x & 63;
    int row = blockIdx.x * 4 + wave;
    const float* tr = obuf + (size_t)row * NBIG;

    float t[12];
#pragma unroll
    for (int i = 0; i < 12; ++i) t[i] = tr[lane + i * 64];

    float acc[NTYPE];
#pragma unroll
    for (int o = 0; o < NTYPE; ++o) {
        const float* w = Wt2t + o * Hn + lane;
        float a = 0.f;
#pragma unroll
        for (int i = 0; i < 12; ++i) a += t[i] * w[i * 64];
        acc[o] = a;
    }
#pragma unroll
    for (int o = 0; o < NTYPE; ++o)
#pragma unroll
        for (int off = 32; off; off >>= 1) acc[o] += __shfl_xor(acc[o], off);

    float mx = -1e30f;
#pragma unroll
    for (int o = 0; o < NTYPE; ++o) { acc[o] += bt2[o]; mx = fmaxf(mx, acc[o]); }
#pragma unroll
    for (int o = 0; o < NTYPE; ++o)
        if (lane == o) out_type[row * NTYPE + o] = acc[o];

    float pr[NTYPE], sum = 0.f;
#pragma unroll
    for (int o = 0; o < NTYPE; ++o) { pr[o] = expf(acc[o] - mx); sum += pr[o]; }
    float inv = 1.f / sum;
#pragma unroll
    for (int o = 0; o < NTYPE; ++o) pr[o] *= inv;

    const float* sp = tr + Hn;
    const float* Wtail = Ws1 + (size_t)SPAN_DIM * Hn;
    float acc2[NSENS] = {};
#pragma unroll
    for (int i = 0; i < 12; ++i) {
        int c = lane + i * 64;
        float tl = 0.f;
#pragma unroll
        for (int o = 0; o < NTYPE; ++o) tl += pr[o] * Wtail[o * Hn + c];
        float v = gelu_exact(sp[c] + tl);
#pragma unroll
        for (int o = 0; o < NSENS; ++o) acc2[o] += v * Ws2t[o * Hn + c];
    }
#pragma unroll
    for (int o = 0; o < NSENS; ++o)
#pragma unroll
        for (int off = 32; off; off >>= 1) acc2[o] += __shfl_xor(acc2[o], off);
#pragma unroll
    for (int o = 0; o < NSENS; ++o)
        if (lane == o) out_sens[row * NSENS + o] = acc2[o] + bs2[o];
}

extern "C" void kernel_launch(void* const* d_in, const int* in_sizes, int n_in,
                              void* d_out, int out_size, void* d_ws, size_t ws_size,
                              hipStream_t stream)
{
    const float* hidden = (const float*)d_in[0];
    const int*   spans  = (const int*)d_in[1];
    const float* wemb   = (const float*)d_in[2];
    const float* Wp     = (const float*)d_in[3];
    const float* bp     = (const float*)d_in[4];
    const float* Wt1    = (const float*)d_in[5];
    const float* bt1    = (const float*)d_in[6];
    const float* Wt2    = (const float*)d_in[7];
    const float* bt2    = (const float*)d_in[8];
    const float* Ws1    = (const float*)d_in[9];
    const float* bs1    = (const float*)d_in[10];
    const float* Ws2    = (const float*)d_in[11];
    const float* bs2    = (const float*)d_in[12];

    float* out      = (float*)d_out;
    float* out_prop = out;
    float* out_type = out + Bn * Sn * 3;
    float* out_sens = out_type + NROW * NTYPE;

    // workspace layout (all 16B-aligned)
    unsigned short* rep = (unsigned short*)d_ws;                 // [4096][2688] bf16
    float* obuf = (float*)(rep + (size_t)NROW * SPAN_DIM);       // [4096][1536] fp32
    unsigned short* WbigT = (unsigned short*)(obuf + (size_t)NROW * NBIG); // [1536][2688] bf16
    float* Wt2t = (float*)(WbigT + (size_t)NBIG * SPAN_DIM);     // [18][768] fp32
    float* Ws2t = Wt2t + NTYPE * Hn;                             // [4][768] fp32

    prep_weights<<<dim3(SPAN_DIM / 32, Hn / 32, 3), 256, 0, stream>>>(
        Wt1, Ws1, WbigT, Wt2, Ws2, Wt2t, Ws2t);

    proposal_kernel<<<Bn * Sn / 4, 256, 0, stream>>>(hidden, Wp, bp, out_prop);
    span_rep_kernel<<<NROW, 192, 0, stream>>>(hidden, spans, wemb, rep);

    dim3 gg(NROW / 128, NBIG / 64);   // 32 x 24 = 768 blocks = 3/CU
    gemm_fused<<<gg, 256, 0, stream>>>(rep, WbigT, bt1, bs1, obuf);

    heads_kernel<<<NROW / 4, 256, 0, stream>>>(
        obuf, Wt2t, bt2, Ws1, Ws2t, bs2, out_type, out_sens);
}

// Round 5
// 218.799 us; speedup vs baseline: 5.3065x; 1.0387x over previous
//
#include <hip/hip_runtime.h>
#include <hip/hip_bf16.h>
#include <math.h>

#define Bn 8
#define Sn 2048
#define Hn 768
#define NROW 4096          // B * N_SPANS
#define SPAN_DIM 2688
#define NBIG 1536          // fused GEMM N (768 type-t | 768 sens-pre)
#define NTYPE 18
#define NSENS 4
#define WPAD 24            // padded per-k weight row (shorts), 48 B

typedef __attribute__((ext_vector_type(8))) short short8;
typedef __attribute__((ext_vector_type(4))) float floatx4;

__device__ __forceinline__ unsigned short f2bf(float x) {
    __hip_bfloat16 h = __float2bfloat16(x);
    return *reinterpret_cast<unsigned short*>(&h);
}

__device__ __forceinline__ float bfu(unsigned short u) {
    union { float f; unsigned int i; } v;
    v.i = ((unsigned int)u) << 16;
    return v.f;
}

__device__ __forceinline__ void glds16(const void* g, void* l) {
    __builtin_amdgcn_global_load_lds(
        (const __attribute__((address_space(1))) unsigned int*)g,
        (__attribute__((address_space(3))) unsigned int*)l, 16, 0, 0);
}

__device__ __forceinline__ float gelu_exact(float v) {
    return 0.5f * v * (1.f + erff(v * 0.70710678118654752f));
}

// ---------------- proposal head: [16384,768] @ [768,3] + b ----------------
__global__ __launch_bounds__(256) void proposal_kernel(
    const float* __restrict__ hidden, const float* __restrict__ Wp,
    const float* __restrict__ bp, float* __restrict__ out)
{
    int wave = threadIdx.x >> 6;
    int lane = threadIdx.x & 63;
    int row  = blockIdx.x * 4 + wave;
    const float4* h4 = (const float4*)(hidden + (size_t)row * Hn);
    float a0 = 0.f, a1 = 0.f, a2 = 0.f;
#pragma unroll
    for (int i = 0; i < 3; ++i) {
        int kc = i * 64 + lane;
        float4 h = h4[kc];
        const float* w = Wp + kc * 12;
        a0 += h.x * w[0] + h.y * w[3] + h.z * w[6] + h.w * w[9];
        a1 += h.x * w[1] + h.y * w[4] + h.z * w[7] + h.w * w[10];
        a2 += h.x * w[2] + h.y * w[5] + h.z * w[8] + h.w * w[11];
    }
#pragma unroll
    for (int off = 32; off; off >>= 1) {
        a0 += __shfl_xor(a0, off);
        a1 += __shfl_xor(a1, off);
        a2 += __shfl_xor(a2, off);
    }
    if (lane < 3) {
        float v = (lane == 0 ? a0 : (lane == 1 ? a1 : a2)) + bp[lane];
        out[row * 3 + lane] = v;
    }
}

// ------- span representations → rep[4096, 2688] bf16, unroll-4 pooling -------
__global__ __launch_bounds__(192) void span_rep_kernel(
    const float* __restrict__ hidden, const int* __restrict__ spans,
    const float* __restrict__ wemb, unsigned short* __restrict__ rep)
{
    int n = blockIdx.x;
    int b = n >> 9;
    int s = spans[n * 2 + 0];
    int e = spans[n * 2 + 1];
    int w = e - s + 1;
    const float4* hb4 = (const float4*)(hidden + (size_t)b * Sn * Hn);
    unsigned short* r = rep + (size_t)n * SPAN_DIM;
    float inv_w = 1.0f / (float)w;
    int tid = threadIdx.x;

    float4 sv = hb4[(size_t)s * 192 + tid];
    float4 ev = hb4[(size_t)e * 192 + tid];
    float4 p0 = make_float4(0.f, 0.f, 0.f, 0.f), p1 = p0, p2 = p0, p3 = p0;
    int rr = s;
    for (; rr + 3 <= e; rr += 4) {
        float4 h0 = hb4[(size_t)(rr + 0) * 192 + tid];
        float4 h1 = hb4[(size_t)(rr + 1) * 192 + tid];
        float4 h2 = hb4[(size_t)(rr + 2) * 192 + tid];
        float4 h3 = hb4[(size_t)(rr + 3) * 192 + tid];
        p0.x += h0.x; p0.y += h0.y; p0.z += h0.z; p0.w += h0.w;
        p1.x += h1.x; p1.y += h1.y; p1.z += h1.z; p1.w += h1.w;
        p2.x += h2.x; p2.y += h2.y; p2.z += h2.z; p2.w += h2.w;
        p3.x += h3.x; p3.y += h3.y; p3.z += h3.z; p3.w += h3.w;
    }
    for (; rr <= e; ++rr) {
        float4 h = hb4[(size_t)rr * 192 + tid];
        p0.x += h.x; p0.y += h.y; p0.z += h.z; p0.w += h.w;
    }
    float4 pv;
    pv.x = ((p0.x + p1.x) + (p2.x + p3.x)) * inv_w;
    pv.y = ((p0.y + p1.y) + (p2.y + p3.y)) * inv_w;
    pv.z = ((p0.z + p1.z) + (p2.z + p3.z)) * inv_w;
    pv.w = ((p0.w + p1.w) + (p2.w + p3.w)) * inv_w;

    *(ushort4*)&r[tid * 4] =
        make_ushort4(f2bf(sv.x), f2bf(sv.y), f2bf(sv.z), f2bf(sv.w));
    *(ushort4*)&r[Hn + tid * 4] =
        make_ushort4(f2bf(ev.x), f2bf(ev.y), f2bf(ev.z), f2bf(ev.w));
    *(ushort4*)&r[2 * Hn + tid * 4] =
        make_ushort4(f2bf(pv.x), f2bf(pv.y), f2bf(pv.z), f2bf(pv.w));
    if (tid < 96) {
        int wi = w > 63 ? 63 : w;
        float4 wv = ((const float4*)wemb)[wi * 96 + tid];
        *(ushort4*)&r[3 * Hn + tid * 4] =
            make_ushort4(f2bf(wv.x), f2bf(wv.y), f2bf(wv.z), f2bf(wv.w));
    }
}

// ----- weight prep: z=0/1 big transposes -> WbigT bf16; z=2 small k-major bf16 -----
__global__ __launch_bounds__(256) void prep_weights(
    const float* __restrict__ Wt1, const float* __restrict__ Ws1,
    unsigned short* __restrict__ WbigT,
    const float* __restrict__ Wt2, const float* __restrict__ Ws2,
    unsigned short* __restrict__ Wt2bf, unsigned short* __restrict__ Wtailbf,
    unsigned short* __restrict__ Ws2bf)
{
    int z = blockIdx.z;
    if (z == 2) {
        int gid = blockIdx.y * 84 + blockIdx.x;
        int idx = gid * 256 + threadIdx.x;
        const int N1 = Hn * WPAD;          // Wt2bf elems (18432)
        const int N2 = 2 * N1;             // + Wtailbf
        const int N3 = N2 + Hn * NSENS;    // + Ws2bf
        if (idx < N1) {
            int k = idx / WPAD, o = idx - k * WPAD;
            Wt2bf[idx] = (o < NTYPE) ? f2bf(Wt2[k * NTYPE + o]) : 0;
        } else if (idx < N2) {
            int j = idx - N1;
            int k = j / WPAD, o = j - k * WPAD;
            // Ws1 tail rows: Ws1[(2688+o)*768 + k]
            Wtailbf[j] = (o < NTYPE) ? f2bf(Ws1[(size_t)(SPAN_DIM + o) * Hn + k]) : 0;
        } else if (idx < N3) {
            int j = idx - N2;
            Ws2bf[j] = f2bf(Ws2[j]);       // already k-major [768][4]
        }
        return;
    }
    const float* W = (z == 0) ? Wt1 : Ws1;
    unsigned short* Wt = WbigT + (size_t)z * Hn * SPAN_DIM;
    __shared__ float tile[32][33];
    int k0 = blockIdx.x * 32, n0 = blockIdx.y * 32;
    int tx = threadIdx.x & 31, ty = threadIdx.x >> 5;
#pragma unroll
    for (int i = 0; i < 32; i += 8)
        tile[ty + i][tx] = W[(size_t)(k0 + ty + i) * Hn + n0 + tx];
    __syncthreads();
#pragma unroll
    for (int i = 0; i < 32; i += 8)
        Wt[(size_t)(n0 + ty + i) * SPAN_DIM + k0 + tx] = f2bf(tile[tx][ty + i]);
}

// ------------- fused bf16 MFMA GEMM: obuf = epilogue(rep @ WbigT^T) -------------
// 128x64 block tile, BK=64, 4 waves (each 64x32). Swizzled glds16 staging.
__global__ __launch_bounds__(256, 3) void gemm_fused(
    const unsigned short* __restrict__ A,
    const unsigned short* __restrict__ Bt,
    const float* __restrict__ bt1, const float* __restrict__ bs1,
    float* __restrict__ obuf)
{
    const int BK = 64;
    __shared__ unsigned short As[128 * BK];   // 16 KB
    __shared__ unsigned short Bs[64 * BK];    // 8 KB

    int tid = threadIdx.x, wave = tid >> 6, lane = tid & 63;
    int m0 = blockIdx.x * 128, n0 = blockIdx.y * 64;
    int wr = (wave >> 1) * 64;
    int wc = (wave & 1) * 32;
    int fr = lane & 15;
    int fc = lane >> 4;             // 0..3

    const unsigned short* gA[4];
#pragma unroll
    for (int j = 0; j < 4; ++j) {
        int d = tid + j * 256;
        int r = d >> 3, c = (d & 7) ^ (r & 7);
        gA[j] = A + (size_t)(m0 + r) * SPAN_DIM + c * 8;
    }
    const unsigned short* gB[2];
#pragma unroll
    for (int j = 0; j < 2; ++j) {
        int d = tid + j * 256;
        int r = d >> 3, c = (d & 7) ^ (r & 7);
        gB[j] = Bt + (size_t)(n0 + r) * SPAN_DIM + c * 8;
    }
    unsigned short* ldsA[4];
    unsigned short* ldsB[2];
#pragma unroll
    for (int j = 0; j < 4; ++j) ldsA[j] = As + j * 2048 + wave * 512;
#pragma unroll
    for (int j = 0; j < 2; ++j) ldsB[j] = Bs + j * 2048 + wave * 512;

    floatx4 acc[4][2] = {};

    for (int k0 = 0; k0 < SPAN_DIM; k0 += BK) {
        glds16(gA[0] + k0, ldsA[0]);
        glds16(gA[1] + k0, ldsA[1]);
        glds16(gA[2] + k0, ldsA[2]);
        glds16(gA[3] + k0, ldsA[3]);
        glds16(gB[0] + k0, ldsB[0]);
        glds16(gB[1] + k0, ldsB[1]);
        __syncthreads();

#pragma unroll
        for (int half = 0; half < 2; ++half) {
            int cb = half * 4 + fc;
            short8 af[4], bf[2];
#pragma unroll
            for (int i = 0; i < 4; ++i) {
                int r = wr + i * 16 + fr;
                af[i] = *(const short8*)&As[((r << 3) | (cb ^ (r & 7))) * 8];
            }
#pragma unroll
            for (int i = 0; i < 2; ++i) {
                int r = wc + i * 16 + fr;
                bf[i] = *(const short8*)&Bs[((r << 3) | (cb ^ (r & 7))) * 8];
            }
#pragma unroll
            for (int mi = 0; mi < 4; ++mi)
#pragma unroll
                for (int ni = 0; ni < 2; ++ni)
                    acc[mi][ni] = __builtin_amdgcn_mfma_f32_16x16x32_bf16(
                        af[mi], bf[ni], acc[mi][ni], 0, 0, 0);
        }
        __syncthreads();
    }

    bool isT = (n0 < Hn);
    const float* bias = isT ? bt1 : (bs1 - Hn);
    int cr = (lane >> 4) * 4;
#pragma unroll
    for (int mi = 0; mi < 4; ++mi) {
#pragma unroll
        for (int ni = 0; ni < 2; ++ni) {
            int col = n0 + wc + ni * 16 + fr;
            float bv = bias[col];
#pragma unroll
            for (int r = 0; r < 4; ++r) {
                int row = m0 + wr + mi * 16 + cr + r;
                float v = acc[mi][ni][r] + bv;
                if (isT) v = gelu_exact(v);
                obuf[(size_t)row * NBIG + col] = v;
            }
        }
    }
}

// --- fused heads v2: coalesced k-major bf16 weights, lane owns k=lane*12..+11 ---
__global__ __launch_bounds__(256) void heads_kernel(
    const float* __restrict__ obuf, const unsigned short* __restrict__ Wt2bf,
    const float* __restrict__ bt2, const unsigned short* __restrict__ Wtailbf,
    const unsigned short* __restrict__ Ws2bf, const float* __restrict__ bs2,
    float* __restrict__ out_type, float* __restrict__ out_sens)
{
    int wave = threadIdx.x >> 6, lane = threadIdx.x & 63;
    int row = blockIdx.x * 4 + wave;
    const float* tr = obuf + (size_t)row * NBIG;

    // ---- type logits ----
    float t[12];
    {
        const float4* t4 = (const float4*)(tr + lane * 12);
        float4 a = t4[0], b = t4[1], c = t4[2];
        t[0] = a.x; t[1] = a.y; t[2]  = a.z; t[3]  = a.w;
        t[4] = b.x; t[5] = b.y; t[6]  = b.z; t[7]  = b.w;
        t[8] = c.x; t[9] = c.y; t[10] = c.z; t[11] = c.w;
    }
    float acc[NTYPE] = {};
    const unsigned short* wp = Wt2bf + (size_t)lane * 12 * WPAD;
#pragma unroll
    for (int j = 0; j < 12; ++j) {
        short8 w0 = *(const short8*)(wp + j * WPAD);
        short8 w1 = *(const short8*)(wp + j * WPAD + 8);
        ushort4 w2 = *(const ushort4*)(wp + j * WPAD + 16);
        float tv = t[j];
#pragma unroll
        for (int o = 0; o < 8; ++o) acc[o] += tv * bfu((unsigned short)w0[o]);
#pragma unroll
        for (int o = 0; o < 8; ++o) acc[8 + o] += tv * bfu((unsigned short)w1[o]);
        acc[16] += tv * bfu(w2.x);
        acc[17] += tv * bfu(w2.y);
    }
#pragma unroll
    for (int o = 0; o < NTYPE; ++o)
#pragma unroll
        for (int off = 32; off; off >>= 1) acc[o] += __shfl_xor(acc[o], off);

    float mx = -1e30f;
#pragma unroll
    for (int o = 0; o < NTYPE; ++o) { acc[o] += bt2[o]; mx = fmaxf(mx, acc[o]); }
    {
        float lv = 0.f;
#pragma unroll
        for (int o = 0; o < NTYPE; ++o) lv = (lane == o) ? acc[o] : lv;
        if (lane < NTYPE) out_type[row * NTYPE + lane] = lv;
    }
    float pr[NTYPE], sum = 0.f;
#pragma unroll
    for (int o = 0; o < NTYPE; ++o) { pr[o] = expf(acc[o] - mx); sum += pr[o]; }
    float inv = 1.f / sum;
#pragma unroll
    for (int o = 0; o < NTYPE; ++o) pr[o] *= inv;

    // ---- tail correction + GELU + sens head ----
    float s[12];
    {
        const float4* s4 = (const float4*)(tr + Hn + lane * 12);
        float4 a = s4[0], b = s4[1], c = s4[2];
        s[0] = a.x; s[1] = a.y; s[2]  = a.z; s[3]  = a.w;
        s[4] = b.x; s[5] = b.y; s[6]  = b.z; s[7]  = b.w;
        s[8] = c.x; s[9] = c.y; s[10] = c.z; s[11] = c.w;
    }
    float acc2[NSENS] = {};
    const unsigned short* wt = Wtailbf + (size_t)lane * 12 * WPAD;
    const unsigned short* w2p = Ws2bf + (size_t)lane * 12 * NSENS;
#pragma unroll
    for (int j = 0; j < 12; ++j) {
        short8 a0 = *(const short8*)(wt + j * WPAD);
        short8 a1 = *(const short8*)(wt + j * WPAD + 8);
        ushort4 a2 = *(const ushort4*)(wt + j * WPAD + 16);
        float tl = 0.f;
#pragma unroll
        for (int o = 0; o < 8; ++o) tl += pr[o] * bfu((unsigned short)a0[o]);
#pragma unroll
        for (int o = 0; o < 8; ++o) tl += pr[8 + o] * bfu((unsigned short)a1[o]);
        tl += pr[16] * bfu(a2.x) + pr[17] * bfu(a2.y);
        float v = gelu_exact(s[j] + tl);
        ushort4 wv = *(const ushort4*)(w2p + j * NSENS);
        acc2[0] += v * bfu(wv.x);
        acc2[1] += v * bfu(wv.y);
        acc2[2] += v * bfu(wv.z);
        acc2[3] += v * bfu(wv.w);
    }
#pragma unroll
    for (int o = 0; o < NSENS; ++o)
#pragma unroll
        for (int off = 32; off; off >>= 1) acc2[o] += __shfl_xor(acc2[o], off);
    {
        float lv = 0.f;
#pragma unroll
        for (int o = 0; o < NSENS; ++o) lv = (lane == o) ? (acc2[o] + bs2[o]) : lv;
        if (lane < NSENS) out_sens[row * NSENS + lane] = lv;
    }
}

extern "C" void kernel_launch(void* const* d_in, const int* in_sizes, int n_in,
                              void* d_out, int out_size, void* d_ws, size_t ws_size,
                              hipStream_t stream)
{
    const float* hidden = (const float*)d_in[0];
    const int*   spans  = (const int*)d_in[1];
    const float* wemb   = (const float*)d_in[2];
    const float* Wp     = (const float*)d_in[3];
    const float* bp     = (const float*)d_in[4];
    const float* Wt1    = (const float*)d_in[5];
    const float* bt1    = (const float*)d_in[6];
    const float* Wt2    = (const float*)d_in[7];
    const float* bt2    = (const float*)d_in[8];
    const float* Ws1    = (const float*)d_in[9];
    const float* bs1    = (const float*)d_in[10];
    const float* Ws2    = (const float*)d_in[11];
    const float* bs2    = (const float*)d_in[12];

    float* out      = (float*)d_out;
    float* out_prop = out;
    float* out_type = out + Bn * Sn * 3;
    float* out_sens = out_type + NROW * NTYPE;

    // workspace layout (all 16B-aligned)
    unsigned short* rep = (unsigned short*)d_ws;                 // [4096][2688] bf16
    float* obuf = (float*)(rep + (size_t)NROW * SPAN_DIM);       // [4096][1536] fp32
    unsigned short* WbigT = (unsigned short*)(obuf + (size_t)NROW * NBIG); // [1536][2688] bf16
    unsigned short* Wt2bf   = WbigT + (size_t)NBIG * SPAN_DIM;   // [768][24] bf16
    unsigned short* Wtailbf = Wt2bf + Hn * WPAD;                 // [768][24] bf16
    unsigned short* Ws2bf   = Wtailbf + Hn * WPAD;               // [768][4]  bf16

    prep_weights<<<dim3(SPAN_DIM / 32, Hn / 32, 3), 256, 0, stream>>>(
        Wt1, Ws1, WbigT, Wt2, Ws2, Wt2bf, Wtailbf, Ws2bf);

    proposal_kernel<<<Bn * Sn / 4, 256, 0, stream>>>(hidden, Wp, bp, out_prop);
    span_rep_kernel<<<NROW, 192, 0, stream>>>(hidden, spans, wemb, rep);

    dim3 gg(NROW / 128, NBIG / 64);   // 32 x 24 = 768 blocks = 3/CU
    gemm_fused<<<gg, 256, 0, stream>>>(rep, WbigT, bt1, bs1, obuf);

    heads_kernel<<<NROW / 4, 256, 0, stream>>>(
        obuf, Wt2bf, bt2, Wtailbf, Ws2bf, bs2, out_type, out_sens);
}